// Round 10
// baseline (57.262 us; speedup 1.0000x reference)
//
#include <hip/hip_runtime.h>
#include <stdint.h>

// YOLOv3 head decode: B=32, NA=3 anchors, 76x76 grid, 85 attrs, stride=8.
// in : [B, 255, 76, 76] f32   (c-major, spatial contiguous)
// out: [B, 3*76*76, 85] f32   (attr contiguous)
//
// BARRIER-FREE wave-autonomous transpose, direct-register loads.
// Unit = (row, 4-column group), one per wave:
//   load   : lane c: global_load_dwordx4 inb+c*SPATIAL (16B; the block's 4
//            sibling waves read adjacent 16B chunks -> L2 merges to 64B lines)
//   xform  : in registers (channel uniform per lane; fine-grained vmcnt)
//   scatter: LDS outbuf[t*85+c], lanes consecutive -> 2/bank = free
//   wait   : s_waitcnt lgkmcnt(0)   (wave-local; no __syncthreads anywhere)
//   store  : contiguous NT dwordx4  (1360 B per unit, 16B-aligned)
// LDS = 1.36 KB/wave -> 5.4 KB/block.

#define GH 76
#define GW 76
#define NA 3
#define ATTRS 85
#define SPATIAL (GH * GW)          // 5776
#define NGRP 19                    // 76/4 column groups per row
#define LOG2E 1.4426950408889634f

typedef float f32x4 __attribute__((ext_vector_type(4)));

__global__ __launch_bounds__(256) void yolo_head_kernel(
    const float* __restrict__ in, float* __restrict__ out, int nwg) {
    // ---- bijective XCD swizzle (nwg % 8 == 0 here) ----
    const int L = blockIdx.x;
    const int q = nwg >> 3, r = nwg & 7, xcd = L & 7;
    const int W = (xcd < r ? xcd * (q + 1) : r * (q + 1) + (xcd - r) * q) + (L >> 3);

    const int lane = threadIdx.x & 63;
    const int wv   = threadIdx.x >> 6;

    const int u   = W * 4 + wv;        // unit = (row, group); consecutive units same XCD
    const int row = u / NGRP;          // row = (b*NA + a)*GH + gy
    const int g   = u - row * NGRP;    // column group, gx = g*4 .. g*4+3
    const int gy  = row % GH;
    const int t2  = row / GH;
    const int a   = t2 % NA;
    const int b   = t2 / NA;

    const float aw = (a == 0) ? 10.0f : (a == 1) ? 16.0f : 33.0f;
    const float ah = (a == 0) ? 13.0f : (a == 1) ? 30.0f : 23.0f;

    __shared__ float outbuf_all[4][ATTRS * 4];   // 1.36 KB per wave
    float* outbuf = outbuf_all[wv];

    const float* inb = in + ((size_t)(b * (NA * ATTRS) + a * ATTRS)) * SPATIAL
                          + (size_t)gy * GW + g * 4;

    // ---- load direct to VGPRs (same global pattern as before; no LDS leg) ----
    f32x4 v[2];
#pragma unroll
    for (int k = 0; k < 2; ++k) {
        const int c = lane + k * 64;
        if (c < ATTRS)
            v[k] = *reinterpret_cast<const f32x4*>(inb + (size_t)c * SPATIAL);
    }

    // ---- transform (channel uniform per lane) + scatter to LDS ----
#pragma unroll
    for (int k = 0; k < 2; ++k) {
        const int c = lane + k * 64;
        if (c < ATTRS) {
            f32x4 E, rs;
#pragma unroll
            for (int t = 0; t < 4; ++t) {
                E[t]  = __builtin_amdgcn_exp2f(LOG2E * v[k][t]);     // e^x
                rs[t] = E[t] * __builtin_amdgcn_rcpf(1.0f + E[t]);   // sigmoid
            }
            if (c < 4) {
                const float gx0 = (float)(g * 4);
#pragma unroll
                for (int t = 0; t < 4; ++t) {
                    if      (c == 0) rs[t] = (rs[t] + gx0 + (float)t) * 8.0f;
                    else if (c == 1) rs[t] = (rs[t] + (float)gy) * 8.0f;
                    else if (c == 2) rs[t] = E[t] * aw;
                    else              rs[t] = E[t] * ah;
                }
            }
#pragma unroll
            for (int t = 0; t < 4; ++t)
                outbuf[t * ATTRS + c] = rs[t];   // lanes consecutive: conflict-free
        }
    }
    asm volatile("s_waitcnt lgkmcnt(0)" ::: "memory");  // wave-local wait

    // ---- store: contiguous NT dwordx4 stream ----
    float* outg = out + (size_t)row * (GW * ATTRS) + g * (4 * ATTRS);
#pragma unroll
    for (int k = 0; k < 2; ++k) {
        const int j = lane + k * 64;
        if (j < ATTRS) {
            const f32x4 s = *reinterpret_cast<const f32x4*>(&outbuf[j * 4]);
            __builtin_nontemporal_store(s, reinterpret_cast<f32x4*>(outg + j * 4));
        }
    }
}

extern "C" void kernel_launch(void* const* d_in, const int* in_sizes, int n_in,
                              void* d_out, int out_size, void* d_ws, size_t ws_size,
                              hipStream_t stream) {
    const float* in = (const float*)d_in[0];
    float* out = (float*)d_out;
    const int B = in_sizes[0] / (NA * ATTRS * SPATIAL);  // 32
    const int nunits = GH * NA * B * NGRP;               // 138624
    const int nwg = nunits / 4;                          // 34656 (div by 8)
    yolo_head_kernel<<<dim3(nwg), 256, 0, stream>>>(in, out, nwg);
}